// Round 1
// baseline (6697.105 us; speedup 1.0000x reference)
//
#include <hip/hip_runtime.h>

#define T_STEPS 8192
#define BATCH   128
#define HID     96
#define G4      384   // 4*H

__device__ __forceinline__ float fast_sigmoid(float v) {
    // 1 / (1 + exp(-v))
    return __builtin_amdgcn_rcpf(1.0f + __expf(-v));
}
__device__ __forceinline__ float fast_tanh(float v) {
    // tanh(x) = 1 - 2/(exp(2x)+1)   (inf-safe: exp->inf gives -1, exp->0 gives +1... )
    return 1.0f - 2.0f * __builtin_amdgcn_rcpf(1.0f + __expf(2.0f * v));
}

__global__ __launch_bounds__(768, 1)
void lstm_seq_kernel(const float* __restrict__ x,
                     const float* __restrict__ W_ih,
                     const float* __restrict__ W_hh,
                     const float* __restrict__ b_ih,
                     const float* __restrict__ b_hh,
                     const float* __restrict__ W_fc,
                     const float* __restrict__ b_fc,
                     float* __restrict__ out)
{
    const int b   = blockIdx.x;       // batch element
    const int tid = threadIdx.x;      // 0..767
    const int g   = tid >> 1;         // gate index 0..383
    const int p   = tid & 1;          // which half of the K=96 dot
    const int typ = g / HID;          // 0=i 1=f 2=g 3=o

    __shared__ __align__(16) float h_lds[HID];
    __shared__ float gate_lds[G4];
    __shared__ float p_lds[2][HID];

    // --- per-thread weights: 48-element slice of W_hh row g ---
    float w[48];
    {
        const float4* wr = reinterpret_cast<const float4*>(W_hh + g * HID + p * 48);
        #pragma unroll
        for (int k = 0; k < 12; ++k) {
            float4 v4 = wr[k];
            w[4*k+0] = v4.x; w[4*k+1] = v4.y; w[4*k+2] = v4.z; w[4*k+3] = v4.w;
        }
    }
    const float wih  = W_ih[g];
    const float bsum = b_ih[g] + b_hh[g];
    const float bfc  = b_fc[0];
    const float wfc  = (tid < HID) ? W_fc[tid] : 0.0f;
    float c = 0.0f;   // cell state owned by threads 0..95

    if (tid < HID) h_lds[tid] = 0.0f;
    __syncthreads();

    float xt = x[0 * BATCH + b];
    for (int t = 0; t < T_STEPS; ++t) {
        // prefetch next x (broadcast load, latency hidden under the step)
        const int tn = (t + 1 < T_STEPS) ? (t + 1) : t;
        const float xnext = x[tn * BATCH + b];

        // ---- phase B: gate partial dot over 48 elements ----
        float a0 = (p == 0) ? fmaf(xt, wih, bsum) : 0.0f;
        float a1 = 0.0f, a2 = 0.0f, a3 = 0.0f;
        const float4* hv = reinterpret_cast<const float4*>(&h_lds[p * 48]);
        #pragma unroll
        for (int k = 0; k < 12; k += 4) {
            float4 h4;
            h4 = hv[k+0]; a0 = fmaf(h4.x, w[4*k+ 0], a0); a0 = fmaf(h4.y, w[4*k+ 1], a0);
                          a0 = fmaf(h4.z, w[4*k+ 2], a0); a0 = fmaf(h4.w, w[4*k+ 3], a0);
            h4 = hv[k+1]; a1 = fmaf(h4.x, w[4*k+ 4], a1); a1 = fmaf(h4.y, w[4*k+ 5], a1);
                          a1 = fmaf(h4.z, w[4*k+ 6], a1); a1 = fmaf(h4.w, w[4*k+ 7], a1);
            h4 = hv[k+2]; a2 = fmaf(h4.x, w[4*k+ 8], a2); a2 = fmaf(h4.y, w[4*k+ 9], a2);
                          a2 = fmaf(h4.z, w[4*k+10], a2); a2 = fmaf(h4.w, w[4*k+11], a2);
            h4 = hv[k+3]; a3 = fmaf(h4.x, w[4*k+12], a3); a3 = fmaf(h4.y, w[4*k+13], a3);
                          a3 = fmaf(h4.z, w[4*k+14], a3); a3 = fmaf(h4.w, w[4*k+15], a3);
        }
        float acc = (a0 + a1) + (a2 + a3);
        acc += __shfl_xor(acc, 1, 64);             // pair (2g,2g+1) -> full 96-dot
        // activation (both threads of the pair compute; even one writes)
        float a = (typ == 2) ? fast_tanh(acc) : fast_sigmoid(acc);
        if (p == 0) gate_lds[g] = a;
        __syncthreads();   // gates published

        // ---- phase D ----
        if (tid < HID) {
            const int j = tid;
            const float ig = gate_lds[j];
            const float fg = gate_lds[HID + j];
            const float gg = gate_lds[2 * HID + j];
            const float og = gate_lds[3 * HID + j];
            c = fmaf(fg, c, ig * gg);
            const float hn = og * fast_tanh(c);
            h_lds[j] = hn;                 // safe: all phase-B reads done (barrier above)
            p_lds[t & 1][j] = hn * wfc;    // FC partial, reduced next step by wave 2
        } else if (tid >= 128 && tid < 192 && t > 0) {
            // wave 2: reduce previous step's FC partials -> out[t-1]
            const int lane = tid - 128;
            const float* pp = p_lds[(t & 1) ^ 1];
            float s = pp[lane] + ((lane < 32) ? pp[64 + lane] : 0.0f);
            #pragma unroll
            for (int d = 1; d < 64; d <<= 1) s += __shfl_xor(s, d, 64);
            if (lane == 0) out[(t - 1) * BATCH + b] = s + bfc + x[(t - 1) * BATCH + b];
        }
        __syncthreads();   // h published for next step
        xt = xnext;
    }

    // final timestep's output
    if (tid >= 128 && tid < 192) {
        const int lane = tid - 128;
        const float* pp = p_lds[(T_STEPS - 1) & 1];
        float s = pp[lane] + ((lane < 32) ? pp[64 + lane] : 0.0f);
        #pragma unroll
        for (int d = 1; d < 64; d <<= 1) s += __shfl_xor(s, d, 64);
        if (lane == 0) out[(T_STEPS - 1) * BATCH + b] =
            s + bfc + x[(T_STEPS - 1) * BATCH + b];
    }
}

extern "C" void kernel_launch(void* const* d_in, const int* in_sizes, int n_in,
                              void* d_out, int out_size, void* d_ws, size_t ws_size,
                              hipStream_t stream) {
    (void)in_sizes; (void)n_in; (void)out_size; (void)d_ws; (void)ws_size;
    const float* x    = (const float*)d_in[0];
    const float* W_ih = (const float*)d_in[1];
    const float* W_hh = (const float*)d_in[2];
    const float* b_ih = (const float*)d_in[3];
    const float* b_hh = (const float*)d_in[4];
    const float* W_fc = (const float*)d_in[5];
    const float* b_fc = (const float*)d_in[6];
    float* out = (float*)d_out;

    lstm_seq_kernel<<<dim3(BATCH), dim3(768), 0, stream>>>(
        x, W_ih, W_hh, b_ih, b_hh, W_fc, b_fc, out);
}